// Round 2
// baseline (521.708 us; speedup 1.0000x reference)
//
#include <hip/hip_runtime.h>
#include <hip/hip_bf16.h>
#include <stdint.h>

// ---------------------------------------------------------------------------
// GCPNet forward, restructured (ALL I/O IS FLOAT32 per the reference):
//   - M_vv @ V == rowsum(M_vv) (x) v0           (V is rank-1)
//   - color LSTM / mlpV / x_c are DEAD CODE     (never reach outputs)
//   - vertex LSTM is row-independent            -> persistent per-tile kernel
// Internals convert to bf16 only for MFMA operands (f32 accumulate).
// ---------------------------------------------------------------------------

typedef __bf16 bf16x8 __attribute__((ext_vector_type(8)));
typedef float f32x4 __attribute__((ext_vector_type(4)));

#define EDIM 128
#define NVERT 8192
#define CNUM 512
#define NG 64
#define TSTEPS 32

// workspace byte offsets
#define WS_RS 0u          // 8192 f32
#define WS_V0 32768u      // 128 f32
#define WS_W1 33280u      // 512 f32  (Wih_v[:, :128] @ v0)
#define WS_BV 35328u      // 512 f32  (bih_v + bhh_v)
#define WS_ACC 37376u     // 64 f32   (per-graph vote sums)
#define WS_V0BF 37632u    // 128 bf16
#define WS_MLPC3T 38912u  // 128*512 bf16 (mlp3(C) transposed: [e][c])

__device__ __forceinline__ float bf2f(unsigned short s) {
  return __uint_as_float(((unsigned)s) << 16);
}
__device__ __forceinline__ unsigned short f2bf(float f) {
  unsigned u = __float_as_uint(f);
  u += 0x7fffu + ((u >> 16) & 1u);  // RNE
  return (unsigned short)(u >> 16);
}
__device__ __forceinline__ float sigm(float x) {
  return __builtin_amdgcn_rcpf(1.f + __expf(-x));
}
__device__ __forceinline__ float tanh_f(float x) {
  return 1.f - 2.f * __builtin_amdgcn_rcpf(1.f + __expf(2.f * x));
}
__device__ __forceinline__ f32x4 mfma16(bf16x8 a, bf16x8 b, f32x4 c) {
  return __builtin_amdgcn_mfma_f32_16x16x32_bf16(a, b, c, 0, 0, 0);
}
// load 8 consecutive f32 from global, convert to bf16x8 fragment
__device__ __forceinline__ bf16x8 ld8(const float* p) {
  float4 a = *(const float4*)p;
  float4 b = *(const float4*)(p + 4);
  bf16x8 r;
  r[0] = (__bf16)a.x; r[1] = (__bf16)a.y; r[2] = (__bf16)a.z; r[3] = (__bf16)a.w;
  r[4] = (__bf16)b.x; r[5] = (__bf16)b.y; r[6] = (__bf16)b.z; r[7] = (__bf16)b.w;
  return r;
}

// ---------------- rowsum of M_vv (memory-bound, 268 MB f32) ----------------
__global__ __launch_bounds__(256) void k_rowsum(
    const float* __restrict__ M, float* __restrict__ rs) {
  const int row = blockIdx.x;
  const float4* p = (const float4*)(M + (size_t)row * NVERT);
  float s = 0.f;
#pragma unroll
  for (int it = 0; it < 8; it++) {
    float4 q = p[it * 256 + threadIdx.x];
    s += q.x + q.y + q.z + q.w;
  }
#pragma unroll
  for (int off = 32; off > 0; off >>= 1) s += __shfl_down(s, off, 64);
  __shared__ float red[4];
  if ((threadIdx.x & 63) == 0) red[threadIdx.x >> 6] = s;
  __syncthreads();
  if (threadIdx.x == 0) rs[row] = red[0] + red[1] + red[2] + red[3];
}

// ---------------- small precompute: v0, w1, bv, zero acc -------------------
__global__ __launch_bounds__(512) void k_prep(
    const float* __restrict__ vw, const float* __restrict__ vb,
    const float* __restrict__ Wih,
    const float* __restrict__ bih, const float* __restrict__ bhh,
    float* __restrict__ ws) {
  __shared__ float v0s[EDIM];
  const int t = threadIdx.x;
  float* v0 = (float*)((char*)ws + WS_V0);
  float* w1 = (float*)((char*)ws + WS_W1);
  float* bv = (float*)((char*)ws + WS_BV);
  float* acc = (float*)((char*)ws + WS_ACC);
  unsigned short* v0bf = (unsigned short*)((char*)ws + WS_V0BF);
  if (t < EDIM) {
    float v = vw[t] + vb[t];
    v0s[t] = v;
    v0[t] = v;
    v0bf[t] = f2bf(v);
  }
  if (t < NG) acc[t] = 0.f;
  __syncthreads();
  {
    const float4* wr = (const float4*)(Wih + (size_t)t * 256);  // left 128 cols
    float s = 0.f;
#pragma unroll
    for (int kc = 0; kc < 32; kc++) {
      float4 q = wr[kc];
      const float* xi = v0s + kc * 4;
      s += q.x * xi[0] + q.y * xi[1] + q.z * xi[2] + q.w * xi[3];
    }
    w1[t] = s;
    bv[t] = bih[t] + bhh[t];
  }
}

// ---------------- mlp3(C) -> mlpC3^T (bf16) in ws --------------------------
__global__ __launch_bounds__(128) void k_mlpc(
    const float* __restrict__ C, const float* __restrict__ W,
    const float* __restrict__ B, float* __restrict__ ws) {
  unsigned short* out_t = (unsigned short*)((char*)ws + WS_MLPC3T);
  const int c = blockIdx.x, e = threadIdx.x;
  __shared__ float xb[2][EDIM];
  xb[0][e] = C[c * EDIM + e];
  __syncthreads();
#pragma unroll
  for (int l = 0; l < 3; l++) {
    const float4* wrow = (const float4*)(W + ((size_t)l * EDIM + e) * EDIM);
    const float* xin = xb[l & 1];
    float s = B[l * EDIM + e];
#pragma unroll
    for (int kc = 0; kc < EDIM / 4; kc++) {
      float4 q = wrow[kc];
      const float* xi = xin + kc * 4;
      s += q.x * xi[0] + q.y * xi[1] + q.z * xi[2] + q.w * xi[3];
    }
    if (l < 2) {
      s = fmaxf(s, 0.f);
      __syncthreads();
      xb[(l + 1) & 1][e] = s;
      __syncthreads();
    } else {
      out_t[(size_t)e * CNUM + c] = f2bf(s);  // transposed for MFMA B reads
    }
  }
}

// ---------------- outputs 1 and 2: V broadcast + C copy (exact f32) --------
__global__ __launch_bounds__(256) void k_bcast(
    const float* __restrict__ ws, const float* __restrict__ Cin,
    float* __restrict__ out) {
  const float4* v0v = (const float4*)((const char*)ws + WS_V0);
  float4* Vout = (float4*)(out + NG);
  float4* Cout = (float4*)(out + NG + NVERT * EDIM);
  const float4* Cv = (const float4*)Cin;
  const int NVCH = (NVERT * EDIM) / 4;  // 262144
  const int CCH = (CNUM * EDIM) / 4;    // 16384
  int u = blockIdx.x * 256 + threadIdx.x;
  if (u < NVCH) Vout[u] = v0v[u & 31];
  else if (u < NVCH + CCH) Cout[u - NVCH] = Cv[u - NVCH];
}

// ---------------- persistent LSTM + vote (256 blocks x 32 rows) ------------
__global__ __launch_bounds__(256, 1) void k_lstm(
    const float* __restrict__ Mvc, const float* __restrict__ Wih,
    const float* __restrict__ Whh,
    const float* __restrict__ W1, const float* __restrict__ b1,
    const float* __restrict__ W2, const float* __restrict__ b2,
    const float* __restrict__ W3, const float* __restrict__ b3,
    float* __restrict__ ws) {
  const int r0 = blockIdx.x * 32;
  const int t = threadIdx.x;
  const int w = t >> 6;
  const int lane = t & 63;
  const int quad = lane >> 4;
  const int l15 = lane & 15;
  const int nc0 = w * 32;  // wave's 32-col slice of 128

  __shared__ unsigned short Avc[32][CNUM + 8];  // M_vc tile (bf16)
  __shared__ unsigned short Tt[32][EDIM + 8];   // T = M_vc @ mlpC3 tile
  __shared__ unsigned short hvs[32][EDIM + 8];  // hidden state tile
  __shared__ float votes[32];

  const float* rs = (const float*)((const char*)ws + WS_RS);
  const float* w1v = (const float*)((const char*)ws + WS_W1);
  const float* bvv = (const float*)((const char*)ws + WS_BV);
  float* accg = (float*)((char*)ws + WS_ACC);
  const unsigned short* v0bf = (const unsigned short*)((const char*)ws + WS_V0BF);
  const unsigned short* m3t = (const unsigned short*)((const char*)ws + WS_MLPC3T);

  // stage M_vc rows [r0, r0+32) (f32 -> bf16) and init hv = v0
  {
    const int row = t >> 3, c0 = t & 7;  // 8 threads/row
    const float4* g = (const float4*)(Mvc + (size_t)(r0 + row) * CNUM);
#pragma unroll
    for (int it = 0; it < 16; it++) {
      int c4 = it * 8 + c0;  // 128 float4 chunks per row
      float4 q = g[c4];
      ushort4 h;
      h.x = f2bf(q.x); h.y = f2bf(q.y); h.z = f2bf(q.z); h.w = f2bf(q.w);
      *(ushort4*)&Avc[row][c4 * 4] = h;
    }
  }
  for (int i = t; i < 32 * EDIM; i += 256) hvs[i >> 7][i & 127] = v0bf[i & 127];
  __syncthreads();

  // T = Avc @ mlpC3  (B from transposed mlpC3: contiguous in k)
  {
    f32x4 acc[2][2];
#pragma unroll
    for (int mt = 0; mt < 2; mt++)
#pragma unroll
      for (int ns = 0; ns < 2; ns++) {
        acc[mt][ns][0] = 0.f; acc[mt][ns][1] = 0.f;
        acc[mt][ns][2] = 0.f; acc[mt][ns][3] = 0.f;
      }
#pragma unroll
    for (int kc = 0; kc < 16; kc++) {
      bf16x8 a0 = *(const bf16x8*)&Avc[l15][kc * 32 + quad * 8];
      bf16x8 a1 = *(const bf16x8*)&Avc[16 + l15][kc * 32 + quad * 8];
      bf16x8 b0 = *(const bf16x8*)&m3t[(size_t)(nc0 + l15) * CNUM + kc * 32 + quad * 8];
      bf16x8 b1f = *(const bf16x8*)&m3t[(size_t)(nc0 + 16 + l15) * CNUM + kc * 32 + quad * 8];
      acc[0][0] = mfma16(a0, b0, acc[0][0]);
      acc[1][0] = mfma16(a1, b0, acc[1][0]);
      acc[0][1] = mfma16(a0, b1f, acc[0][1]);
      acc[1][1] = mfma16(a1, b1f, acc[1][1]);
    }
#pragma unroll
    for (int mt = 0; mt < 2; mt++)
#pragma unroll
      for (int ns = 0; ns < 2; ns++)
#pragma unroll
        for (int r = 0; r < 4; r++)
          Tt[mt * 16 + quad * 4 + r][nc0 + ns * 16 + l15] = f2bf(acc[mt][ns][r]);
  }
  __syncthreads();

  // xg = x_v @ Wih^T + bih + bhh  (loop-invariant gate preactivation)
  // left half of x_v is rs[i]*v0[e] -> contributes rs[i]*w1[g]
  f32x4 xg[2][4][2];  // [mtile][gate i,f,g,o][nsub]
  {
    float rsv[2][4];
#pragma unroll
    for (int mt = 0; mt < 2; mt++)
#pragma unroll
      for (int r = 0; r < 4; r++) rsv[mt][r] = rs[r0 + mt * 16 + quad * 4 + r];
#pragma unroll
    for (int gi = 0; gi < 4; gi++)
#pragma unroll
      for (int ns = 0; ns < 2; ns++) {
        const int col = gi * 128 + nc0 + ns * 16 + l15;
        const float w1c = w1v[col], bvc = bvv[col];
#pragma unroll
        for (int mt = 0; mt < 2; mt++)
#pragma unroll
          for (int r = 0; r < 4; r++) xg[mt][gi][ns][r] = fmaf(rsv[mt][r], w1c, bvc);
      }
#pragma unroll
    for (int kc = 0; kc < 4; kc++) {
      bf16x8 a0 = *(const bf16x8*)&Tt[l15][kc * 32 + quad * 8];
      bf16x8 a1 = *(const bf16x8*)&Tt[16 + l15][kc * 32 + quad * 8];
#pragma unroll
      for (int gi = 0; gi < 4; gi++)
#pragma unroll
        for (int ns = 0; ns < 2; ns++) {
          const int gcol = gi * 128 + nc0 + ns * 16 + l15;
          bf16x8 bfr = ld8(&Wih[(size_t)gcol * 256 + 128 + kc * 32 + quad * 8]);
          xg[0][gi][ns] = mfma16(a0, bfr, xg[0][gi][ns]);
          xg[1][gi][ns] = mfma16(a1, bfr, xg[1][gi][ns]);
        }
    }
  }

  // Whh B-fragments held in registers for all 32 steps (128 VGPR)
  bf16x8 Bh[4][2][4];
#pragma unroll
  for (int gi = 0; gi < 4; gi++)
#pragma unroll
    for (int ns = 0; ns < 2; ns++) {
      const int gcol = gi * 128 + nc0 + ns * 16 + l15;
#pragma unroll
      for (int kc = 0; kc < 4; kc++)
        Bh[gi][ns][kc] = ld8(&Whh[(size_t)gcol * EDIM + kc * 32 + quad * 8]);
    }

  f32x4 cv[2][2];
#pragma unroll
  for (int mt = 0; mt < 2; mt++)
#pragma unroll
    for (int ns = 0; ns < 2; ns++) {
      cv[mt][ns][0] = 0.f; cv[mt][ns][1] = 0.f;
      cv[mt][ns][2] = 0.f; cv[mt][ns][3] = 0.f;
    }

  // ---- 32 LSTM steps, no grid sync needed (row-independent recurrence) ----
#pragma unroll 1
  for (int step = 0; step < TSTEPS; step++) {
    bf16x8 A[2][4];
#pragma unroll
    for (int mt = 0; mt < 2; mt++)
#pragma unroll
      for (int kc = 0; kc < 4; kc++)
        A[mt][kc] = *(const bf16x8*)&hvs[mt * 16 + l15][kc * 32 + quad * 8];
    __syncthreads();  // all reads of hv done before overwrite
#pragma unroll
    for (int mt = 0; mt < 2; mt++)
#pragma unroll
      for (int ns = 0; ns < 2; ns++) {
        f32x4 gI = xg[mt][0][ns], gF = xg[mt][1][ns];
        f32x4 gG = xg[mt][2][ns], gO = xg[mt][3][ns];
#pragma unroll
        for (int kc = 0; kc < 4; kc++) {
          gI = mfma16(A[mt][kc], Bh[0][ns][kc], gI);
          gF = mfma16(A[mt][kc], Bh[1][ns][kc], gF);
          gG = mfma16(A[mt][kc], Bh[2][ns][kc], gG);
          gO = mfma16(A[mt][kc], Bh[3][ns][kc], gO);
        }
#pragma unroll
        for (int r = 0; r < 4; r++) {
          float ig = sigm(gI[r]), fg = sigm(gF[r]);
          float gg = tanh_f(gG[r]), og = sigm(gO[r]);
          float c2 = fmaf(fg, cv[mt][ns][r], ig * gg);
          cv[mt][ns][r] = c2;
          hvs[mt * 16 + quad * 4 + r][nc0 + ns * 16 + l15] = f2bf(og * tanh_f(c2));
        }
      }
    __syncthreads();  // writes visible for next step
  }

  // ---- fused vote MLP: two relu layers via MFMA ----
  for (int layer = 0; layer < 2; layer++) {
    const float* Wg = layer ? W2 : W1;
    const float* bg = layer ? b2 : b1;
    bf16x8 A[2][4];
#pragma unroll
    for (int mt = 0; mt < 2; mt++)
#pragma unroll
      for (int kc = 0; kc < 4; kc++)
        A[mt][kc] = *(const bf16x8*)&hvs[mt * 16 + l15][kc * 32 + quad * 8];
    f32x4 acc[2][2];
#pragma unroll
    for (int ns = 0; ns < 2; ns++) {
      float bb = bg[nc0 + ns * 16 + l15];
#pragma unroll
      for (int mt = 0; mt < 2; mt++) {
        acc[mt][ns][0] = bb; acc[mt][ns][1] = bb;
        acc[mt][ns][2] = bb; acc[mt][ns][3] = bb;
      }
    }
#pragma unroll
    for (int kc = 0; kc < 4; kc++)
#pragma unroll
      for (int ns = 0; ns < 2; ns++) {
        bf16x8 bfr = ld8(&Wg[(size_t)(nc0 + ns * 16 + l15) * EDIM + kc * 32 + quad * 8]);
        acc[0][ns] = mfma16(A[0][kc], bfr, acc[0][ns]);
        acc[1][ns] = mfma16(A[1][kc], bfr, acc[1][ns]);
      }
    __syncthreads();
#pragma unroll
    for (int mt = 0; mt < 2; mt++)
#pragma unroll
      for (int ns = 0; ns < 2; ns++)
#pragma unroll
        for (int r = 0; r < 4; r++)
          hvs[mt * 16 + quad * 4 + r][nc0 + ns * 16 + l15] = f2bf(fmaxf(acc[mt][ns][r], 0.f));
    __syncthreads();
  }

  // final vote row-dot + per-graph partial sum (block is inside one graph)
  {
    const int row = t >> 3, seg = t & 7;
    float part = 0.f;
#pragma unroll
    for (int j = 0; j < 16; j++) {
      const int k = seg * 16 + j;
      part += bf2f(hvs[row][k]) * W3[k];
    }
    part += __shfl_down(part, 4, 8);
    part += __shfl_down(part, 2, 8);
    part += __shfl_down(part, 1, 8);
    if ((t & 7) == 0) votes[row] = part + b3[0];
    __syncthreads();
    if (t < 64) {
      float v = (t < 32) ? votes[t] : 0.f;
#pragma unroll
      for (int off = 32; off > 0; off >>= 1) v += __shfl_down(v, off, 64);
      if (t == 0) atomicAdd(&accg[blockIdx.x >> 2], v);
    }
  }
}

// ---------------- per-graph mean + sigmoid ---------------------------------
__global__ __launch_bounds__(64) void k_final(const float* __restrict__ ws,
                                              const int* __restrict__ slice,
                                              float* __restrict__ out) {
  const float* accg = (const float*)((const char*)ws + WS_ACC);
  const int g = threadIdx.x;
  float m = accg[g] / (float)slice[g];
  out[g] = 1.f / (1.f + __expf(-m));
}

extern "C" void kernel_launch(void* const* d_in, const int* in_sizes, int n_in,
                              void* d_out, int out_size, void* d_ws, size_t ws_size,
                              hipStream_t stream) {
  const float* M_vv = (const float*)d_in[0];
  const float* M_vc = (const float*)d_in[1];
  const float* C = (const float*)d_in[2];
  const int* slice = (const int*)d_in[3];
  const float* vw = (const float*)d_in[4];
  const float* vb = (const float*)d_in[5];
  const float* mW = (const float*)d_in[6];
  const float* mB = (const float*)d_in[7];
  // d_in[8], d_in[9] (mlpV), d_in[14..17] (color LSTM): dead code
  const float* Wih = (const float*)d_in[10];
  const float* Whh = (const float*)d_in[11];
  const float* bih = (const float*)d_in[12];
  const float* bhh = (const float*)d_in[13];
  const float* W1 = (const float*)d_in[18];
  const float* b1 = (const float*)d_in[19];
  const float* W2 = (const float*)d_in[20];
  const float* b2 = (const float*)d_in[21];
  const float* W3 = (const float*)d_in[22];
  const float* b3 = (const float*)d_in[23];
  float* ws = (float*)d_ws;
  float* out = (float*)d_out;

  k_rowsum<<<NVERT, 256, 0, stream>>>(M_vv, (float*)((char*)ws + WS_RS));
  k_prep<<<1, 512, 0, stream>>>(vw, vb, Wih, bih, bhh, ws);
  k_mlpc<<<CNUM, 128, 0, stream>>>(C, mW, mB, ws);
  k_bcast<<<1088, 256, 0, stream>>>(ws, C, out);
  k_lstm<<<256, 256, 0, stream>>>(M_vc, Wih, Whh, W1, b1, W2, b2, W3, b3, ws);
  k_final<<<1, 64, 0, stream>>>(ws, slice, out);
}

// Round 3
// 514.040 us; speedup vs baseline: 1.0149x; 1.0149x over previous
//
#include <hip/hip_runtime.h>
#include <hip/hip_bf16.h>
#include <stdint.h>

// ---------------------------------------------------------------------------
// GCPNet forward (ALL I/O FLOAT32):
//   - M_vv @ V == rowsum(M_vv) (x) v0           (V is rank-1)
//   - color LSTM / mlpV / x_c are DEAD CODE     (never reach outputs)
//   - vertex LSTM is row-independent            -> persistent per-tile kernel
// R2->R3: k_lstm 256->512 thr (16 cols/wave: Bh 128->64 VGPR, xg 64->32 —
// kills spill risk, 2 waves/SIMD), hv double-buffer (1 barrier/step),
// k_bcast fused into k_rowsum (V) + k_mlpc (C copy).
// ---------------------------------------------------------------------------

typedef __bf16 bf16x8 __attribute__((ext_vector_type(8)));
typedef float f32x4 __attribute__((ext_vector_type(4)));

#define EDIM 128
#define NVERT 8192
#define CNUM 512
#define NG 64
#define TSTEPS 32

// workspace byte offsets
#define WS_RS 0u          // 8192 f32
#define WS_V0 32768u      // 128 f32
#define WS_W1 33280u      // 512 f32  (Wih_v[:, :128] @ v0)
#define WS_BV 35328u      // 512 f32  (bih_v + bhh_v)
#define WS_ACC 37376u     // 64 f32   (per-graph vote sums)
#define WS_V0BF 37632u    // 128 bf16
#define WS_MLPC3T 38912u  // 128*512 bf16 (mlp3(C) transposed: [e][c])

__device__ __forceinline__ float bf2f(unsigned short s) {
  return __uint_as_float(((unsigned)s) << 16);
}
__device__ __forceinline__ unsigned short f2bf(float f) {
  unsigned u = __float_as_uint(f);
  u += 0x7fffu + ((u >> 16) & 1u);  // RNE
  return (unsigned short)(u >> 16);
}
__device__ __forceinline__ float sigm(float x) {
  return __builtin_amdgcn_rcpf(1.f + __expf(-x));
}
__device__ __forceinline__ float tanh_f(float x) {
  return 1.f - 2.f * __builtin_amdgcn_rcpf(1.f + __expf(2.f * x));
}
__device__ __forceinline__ f32x4 mfma16(bf16x8 a, bf16x8 b, f32x4 c) {
  return __builtin_amdgcn_mfma_f32_16x16x32_bf16(a, b, c, 0, 0, 0);
}
// load 8 consecutive f32 from global, convert to bf16x8 fragment
__device__ __forceinline__ bf16x8 ld8(const float* p) {
  float4 a = *(const float4*)p;
  float4 b = *(const float4*)(p + 4);
  bf16x8 r;
  r[0] = (__bf16)a.x; r[1] = (__bf16)a.y; r[2] = (__bf16)a.z; r[3] = (__bf16)a.w;
  r[4] = (__bf16)b.x; r[5] = (__bf16)b.y; r[6] = (__bf16)b.z; r[7] = (__bf16)b.w;
  return r;
}

// ---------------- rowsum of M_vv (268 MB stream) + V output row ------------
__global__ __launch_bounds__(256) void k_rowsum(
    const float* __restrict__ M, const float* __restrict__ v0,
    float* __restrict__ rs, float* __restrict__ Vout) {
  const int row = blockIdx.x;
  const float4* p = (const float4*)(M + (size_t)row * NVERT);
  float s = 0.f;
#pragma unroll
  for (int it = 0; it < 8; it++) {
    float4 q = p[it * 256 + threadIdx.x];
    s += q.x + q.y + q.z + q.w;
  }
  // output 1: V row = v0 (exact f32)
  if (threadIdx.x < 32)
    ((float4*)(Vout + (size_t)row * EDIM))[threadIdx.x] =
        ((const float4*)v0)[threadIdx.x];
#pragma unroll
  for (int off = 32; off > 0; off >>= 1) s += __shfl_down(s, off, 64);
  __shared__ float red[4];
  if ((threadIdx.x & 63) == 0) red[threadIdx.x >> 6] = s;
  __syncthreads();
  if (threadIdx.x == 0) rs[row] = red[0] + red[1] + red[2] + red[3];
}

// ---------------- small precompute: v0, w1, bv, zero acc -------------------
__global__ __launch_bounds__(512) void k_prep(
    const float* __restrict__ vw, const float* __restrict__ vb,
    const float* __restrict__ Wih,
    const float* __restrict__ bih, const float* __restrict__ bhh,
    float* __restrict__ ws) {
  __shared__ float v0s[EDIM];
  const int t = threadIdx.x;
  float* v0 = (float*)((char*)ws + WS_V0);
  float* w1 = (float*)((char*)ws + WS_W1);
  float* bv = (float*)((char*)ws + WS_BV);
  float* acc = (float*)((char*)ws + WS_ACC);
  unsigned short* v0bf = (unsigned short*)((char*)ws + WS_V0BF);
  if (t < EDIM) {
    float v = vw[t] + vb[t];
    v0s[t] = v;
    v0[t] = v;
    v0bf[t] = f2bf(v);
  }
  if (t < NG) acc[t] = 0.f;
  __syncthreads();
  {
    const float4* wr = (const float4*)(Wih + (size_t)t * 256);  // left 128 cols
    float s = 0.f;
#pragma unroll
    for (int kc = 0; kc < 32; kc++) {
      float4 q = wr[kc];
      const float* xi = v0s + kc * 4;
      s += q.x * xi[0] + q.y * xi[1] + q.z * xi[2] + q.w * xi[3];
    }
    w1[t] = s;
    bv[t] = bih[t] + bhh[t];
  }
}

// ---------------- mlp3(C) -> mlpC3^T (bf16) in ws, + C output copy ---------
__global__ __launch_bounds__(128) void k_mlpc(
    const float* __restrict__ C, const float* __restrict__ W,
    const float* __restrict__ B, float* __restrict__ ws,
    float* __restrict__ Cout) {
  unsigned short* out_t = (unsigned short*)((char*)ws + WS_MLPC3T);
  const int c = blockIdx.x, e = threadIdx.x;
  __shared__ float xb[2][EDIM];
  float cval = C[c * EDIM + e];
  xb[0][e] = cval;
  Cout[c * EDIM + e] = cval;  // output 2 (exact f32 copy)
  __syncthreads();
#pragma unroll
  for (int l = 0; l < 3; l++) {
    const float4* wrow = (const float4*)(W + ((size_t)l * EDIM + e) * EDIM);
    const float* xin = xb[l & 1];
    float s = B[l * EDIM + e];
#pragma unroll
    for (int kc = 0; kc < EDIM / 4; kc++) {
      float4 q = wrow[kc];
      const float* xi = xin + kc * 4;
      s += q.x * xi[0] + q.y * xi[1] + q.z * xi[2] + q.w * xi[3];
    }
    if (l < 2) {
      s = fmaxf(s, 0.f);
      __syncthreads();
      xb[(l + 1) & 1][e] = s;
      __syncthreads();
    } else {
      out_t[(size_t)e * CNUM + c] = f2bf(s);  // transposed for MFMA B reads
    }
  }
}

// ---------------- persistent LSTM + vote (256 blocks x 512 thr) ------------
// 8 waves/block; wave w owns cols [16w, 16w+16) of the 128-wide hidden dim.
__global__ __launch_bounds__(512, 1) void k_lstm(
    const float* __restrict__ Mvc, const float* __restrict__ Wih,
    const float* __restrict__ Whh,
    const float* __restrict__ W1, const float* __restrict__ b1,
    const float* __restrict__ W2, const float* __restrict__ b2,
    const float* __restrict__ W3, const float* __restrict__ b3,
    float* __restrict__ ws) {
  const int r0 = blockIdx.x * 32;
  const int t = threadIdx.x;
  const int w = t >> 6;
  const int lane = t & 63;
  const int quad = lane >> 4;
  const int l15 = lane & 15;
  const int nc0 = w * 16;  // wave's 16-col slice of 128

  __shared__ unsigned short Avc[32][CNUM + 8];     // M_vc tile (bf16)
  __shared__ unsigned short Tt[32][EDIM + 8];      // T = M_vc @ mlpC3
  __shared__ unsigned short hv2[2][32][EDIM + 8];  // double-buffered hidden
  __shared__ float votes[32];

  const float* rs = (const float*)((const char*)ws + WS_RS);
  const float* w1v = (const float*)((const char*)ws + WS_W1);
  const float* bvv = (const float*)((const char*)ws + WS_BV);
  float* accg = (float*)((char*)ws + WS_ACC);
  const unsigned short* v0bf = (const unsigned short*)((const char*)ws + WS_V0BF);
  const unsigned short* m3t = (const unsigned short*)((const char*)ws + WS_MLPC3T);

  // stage M_vc rows [r0, r0+32) (f32 -> bf16) and init hv = v0
  {
    const int row = t >> 4, c0 = t & 15;  // 16 threads/row
    const float4* g = (const float4*)(Mvc + (size_t)(r0 + row) * CNUM);
#pragma unroll
    for (int it = 0; it < 8; it++) {
      int c4 = it * 16 + c0;  // 128 float4 chunks per row
      float4 q = g[c4];
      ushort4 h;
      h.x = f2bf(q.x); h.y = f2bf(q.y); h.z = f2bf(q.z); h.w = f2bf(q.w);
      *(ushort4*)&Avc[row][c4 * 4] = h;
    }
  }
  for (int i = t; i < 32 * EDIM; i += 512) hv2[0][i >> 7][i & 127] = v0bf[i & 127];
  __syncthreads();

  // T = Avc @ mlpC3  (B from transposed mlpC3: contiguous in k)
  {
    f32x4 acc[2];
#pragma unroll
    for (int mt = 0; mt < 2; mt++) {
      acc[mt][0] = 0.f; acc[mt][1] = 0.f; acc[mt][2] = 0.f; acc[mt][3] = 0.f;
    }
#pragma unroll
    for (int kc = 0; kc < 16; kc++) {
      bf16x8 a0 = *(const bf16x8*)&Avc[l15][kc * 32 + quad * 8];
      bf16x8 a1 = *(const bf16x8*)&Avc[16 + l15][kc * 32 + quad * 8];
      bf16x8 b0 = *(const bf16x8*)&m3t[(size_t)(nc0 + l15) * CNUM + kc * 32 + quad * 8];
      acc[0] = mfma16(a0, b0, acc[0]);
      acc[1] = mfma16(a1, b0, acc[1]);
    }
#pragma unroll
    for (int mt = 0; mt < 2; mt++)
#pragma unroll
      for (int r = 0; r < 4; r++)
        Tt[mt * 16 + quad * 4 + r][nc0 + l15] = f2bf(acc[mt][r]);
  }
  __syncthreads();

  // xg = x_v @ Wih^T + bih + bhh  (loop-invariant gate preactivation)
  // left half of x_v is rs[i]*v0[e] -> contributes rs[i]*w1[g]
  f32x4 xg[2][4];  // [mtile][gate i,f,g,o]
  {
    float rsv[2][4];
#pragma unroll
    for (int mt = 0; mt < 2; mt++)
#pragma unroll
      for (int r = 0; r < 4; r++) rsv[mt][r] = rs[r0 + mt * 16 + quad * 4 + r];
#pragma unroll
    for (int gi = 0; gi < 4; gi++) {
      const int col = gi * 128 + nc0 + l15;
      const float w1c = w1v[col], bvc = bvv[col];
#pragma unroll
      for (int mt = 0; mt < 2; mt++)
#pragma unroll
        for (int r = 0; r < 4; r++) xg[mt][gi][r] = fmaf(rsv[mt][r], w1c, bvc);
    }
#pragma unroll
    for (int kc = 0; kc < 4; kc++) {
      bf16x8 a0 = *(const bf16x8*)&Tt[l15][kc * 32 + quad * 8];
      bf16x8 a1 = *(const bf16x8*)&Tt[16 + l15][kc * 32 + quad * 8];
#pragma unroll
      for (int gi = 0; gi < 4; gi++) {
        const int gcol = gi * 128 + nc0 + l15;
        bf16x8 bfr = ld8(&Wih[(size_t)gcol * 256 + 128 + kc * 32 + quad * 8]);
        xg[0][gi] = mfma16(a0, bfr, xg[0][gi]);
        xg[1][gi] = mfma16(a1, bfr, xg[1][gi]);
      }
    }
  }

  // Whh B-fragments held in registers for all 32 steps (64 VGPR)
  bf16x8 Bh[4][4];
#pragma unroll
  for (int gi = 0; gi < 4; gi++) {
    const int gcol = gi * 128 + nc0 + l15;
#pragma unroll
    for (int kc = 0; kc < 4; kc++)
      Bh[gi][kc] = ld8(&Whh[(size_t)gcol * EDIM + kc * 32 + quad * 8]);
  }

  f32x4 cv[2];
#pragma unroll
  for (int mt = 0; mt < 2; mt++) {
    cv[mt][0] = 0.f; cv[mt][1] = 0.f; cv[mt][2] = 0.f; cv[mt][3] = 0.f;
  }

  // ---- 32 LSTM steps; read buf p, write buf p^1, ONE barrier/step ----
  int p = 0;
#pragma unroll 1
  for (int step = 0; step < TSTEPS; step++) {
    bf16x8 A[2][4];
#pragma unroll
    for (int mt = 0; mt < 2; mt++)
#pragma unroll
      for (int kc = 0; kc < 4; kc++)
        A[mt][kc] = *(const bf16x8*)&hv2[p][mt * 16 + l15][kc * 32 + quad * 8];
#pragma unroll
    for (int mt = 0; mt < 2; mt++) {
      f32x4 gI = xg[mt][0], gF = xg[mt][1], gG = xg[mt][2], gO = xg[mt][3];
#pragma unroll
      for (int kc = 0; kc < 4; kc++) {
        gI = mfma16(A[mt][kc], Bh[0][kc], gI);
        gF = mfma16(A[mt][kc], Bh[1][kc], gF);
        gG = mfma16(A[mt][kc], Bh[2][kc], gG);
        gO = mfma16(A[mt][kc], Bh[3][kc], gO);
      }
#pragma unroll
      for (int r = 0; r < 4; r++) {
        float ig = sigm(gI[r]), fg = sigm(gF[r]);
        float gg = tanh_f(gG[r]), og = sigm(gO[r]);
        float c2 = fmaf(fg, cv[mt][r], ig * gg);
        cv[mt][r] = c2;
        hv2[p ^ 1][mt * 16 + quad * 4 + r][nc0 + l15] = f2bf(og * tanh_f(c2));
      }
    }
    p ^= 1;
    __syncthreads();
  }
  // after 32 steps (even), final h is in hv2[0]

  // ---- fused vote MLP: two relu layers via MFMA ----
  for (int layer = 0; layer < 2; layer++) {
    const float* Wg = layer ? W2 : W1;
    const float* bg = layer ? b2 : b1;
    bf16x8 A[2][4];
#pragma unroll
    for (int mt = 0; mt < 2; mt++)
#pragma unroll
      for (int kc = 0; kc < 4; kc++)
        A[mt][kc] = *(const bf16x8*)&hv2[0][mt * 16 + l15][kc * 32 + quad * 8];
    f32x4 acc[2];
    {
      float bb = bg[nc0 + l15];
#pragma unroll
      for (int mt = 0; mt < 2; mt++) {
        acc[mt][0] = bb; acc[mt][1] = bb; acc[mt][2] = bb; acc[mt][3] = bb;
      }
    }
#pragma unroll
    for (int kc = 0; kc < 4; kc++) {
      bf16x8 bfr = ld8(&Wg[(size_t)(nc0 + l15) * EDIM + kc * 32 + quad * 8]);
      acc[0] = mfma16(A[0][kc], bfr, acc[0]);
      acc[1] = mfma16(A[1][kc], bfr, acc[1]);
    }
    __syncthreads();  // all A reads done before overwrite
#pragma unroll
    for (int mt = 0; mt < 2; mt++)
#pragma unroll
      for (int r = 0; r < 4; r++)
        hv2[0][mt * 16 + quad * 4 + r][nc0 + l15] = f2bf(fmaxf(acc[mt][r], 0.f));
    __syncthreads();
  }

  // final vote row-dot + per-graph partial sum (block is inside one graph)
  {
    const int row = t >> 4, seg = t & 15;  // 16 threads/row, 8 cols each
    float part = 0.f;
#pragma unroll
    for (int j = 0; j < 8; j++) {
      const int k = seg * 8 + j;
      part += bf2f(hv2[0][row][k]) * W3[k];
    }
    part += __shfl_down(part, 8, 16);
    part += __shfl_down(part, 4, 16);
    part += __shfl_down(part, 2, 16);
    part += __shfl_down(part, 1, 16);
    if (seg == 0) votes[row] = part + b3[0];
    __syncthreads();
    if (t < 64) {
      float v = (t < 32) ? votes[t] : 0.f;
#pragma unroll
      for (int off = 32; off > 0; off >>= 1) v += __shfl_down(v, off, 64);
      if (t == 0) atomicAdd(&accg[blockIdx.x >> 2], v);
    }
  }
}

// ---------------- per-graph mean + sigmoid ---------------------------------
__global__ __launch_bounds__(64) void k_final(const float* __restrict__ ws,
                                              const int* __restrict__ slice,
                                              float* __restrict__ out) {
  const float* accg = (const float*)((const char*)ws + WS_ACC);
  const int g = threadIdx.x;
  float m = accg[g] / (float)slice[g];
  out[g] = 1.f / (1.f + __expf(-m));
}

extern "C" void kernel_launch(void* const* d_in, const int* in_sizes, int n_in,
                              void* d_out, int out_size, void* d_ws, size_t ws_size,
                              hipStream_t stream) {
  const float* M_vv = (const float*)d_in[0];
  const float* M_vc = (const float*)d_in[1];
  const float* C = (const float*)d_in[2];
  const int* slice = (const int*)d_in[3];
  const float* vw = (const float*)d_in[4];
  const float* vb = (const float*)d_in[5];
  const float* mW = (const float*)d_in[6];
  const float* mB = (const float*)d_in[7];
  // d_in[8], d_in[9] (mlpV), d_in[14..17] (color LSTM): dead code
  const float* Wih = (const float*)d_in[10];
  const float* Whh = (const float*)d_in[11];
  const float* bih = (const float*)d_in[12];
  const float* bhh = (const float*)d_in[13];
  const float* W1 = (const float*)d_in[18];
  const float* b1 = (const float*)d_in[19];
  const float* W2 = (const float*)d_in[20];
  const float* b2 = (const float*)d_in[21];
  const float* W3 = (const float*)d_in[22];
  const float* b3 = (const float*)d_in[23];
  float* ws = (float*)d_ws;
  float* out = (float*)d_out;

  k_prep<<<1, 512, 0, stream>>>(vw, vb, Wih, bih, bhh, ws);
  k_rowsum<<<NVERT, 256, 0, stream>>>(M_vv, (const float*)((char*)ws + WS_V0),
                                      (float*)((char*)ws + WS_RS), out + NG);
  k_mlpc<<<CNUM, 128, 0, stream>>>(C, mW, mB, ws, out + NG + NVERT * EDIM);
  k_lstm<<<256, 512, 0, stream>>>(M_vc, Wih, Whh, W1, b1, W2, b2, W3, b3, ws);
  k_final<<<1, 64, 0, stream>>>(ws, slice, out);
}